// Round 3
// baseline (60047.028 us; speedup 1.0000x reference)
//
#include <hip/hip_runtime.h>

typedef unsigned int u32;
typedef unsigned short u16;
#define DEV __device__ __forceinline__

// ---------------- sizes ----------------
#define T_DEC 300
#define NB    16
#define T_ENC 200
#define EDIM  512
#define ARNN  1024
#define PDIM  256
#define ADIM  128
#define NMEL  80
#define KATT  1792            // 256 prenet + 512 ctx + 1024 h_att
#define KDEC  2560            // 1024 h_att + 512 ctx + 1024 h_dec
#define NBLK  1024
#define NTHR  128
#define SPIN  2000000         // poll-iteration limit (~50-100 ms)

// ---------------- ws byte offsets ----------------
// counters page [0,4096): S1cnt@0, S2cnt@128, abort@256, S2rep[32]@512 (stride 64B)
#define WS_S1CNT  0
#define WS_S2CNT  128
#define WS_ABORT  256
#define WS_S2REP  512
#define WS_ALIGN  4608                      // f32 [2][16][200] = 25600
#define WS_XA     30208                     // f32 [2][1792][16] = 229376
#define WS_XD     259584                    // f32 [2][2560][16] = 327680
#define WS_PM     587264                    // u16 [3200][128] = 819200
#define WS_END    1406464
#define WS_ZERO   587264

// ---------------- out layout (f32 elements) ----------------
#define OUT_GATE  (NB*NMEL*T_DEC)           // 384000
#define OUT_ALIGN (OUT_GATE + NB*T_DEC)     // 388800

// ---------------- helpers ----------------
DEV float bflo(u32 u){ return __uint_as_float(u << 16); }
DEV float bfhi(u32 u){ return __uint_as_float(u & 0xffff0000u); }
DEV u16 f2bf(float f){
  u32 u = __float_as_uint(f);
  return (u16)((u + 0x7fffu + ((u >> 16) & 1u)) >> 16);
}
DEV float fsig(float x){ return 1.0f / (1.0f + __expf(-x)); }
DEV float ftanh(float x){
  float xx = fminf(15.0f, fmaxf(-15.0f, x));
  float e = __expf(2.0f * xx);
  return (e - 1.0f) / (e + 1.0f);
}

// ---- coherent (sc1, write-through) accessors: no wbl2/inv, individually coherent ----
DEV void  ast (float* p, float v){ __hip_atomic_store(p, v, __ATOMIC_RELAXED, __HIP_MEMORY_SCOPE_AGENT); }
DEV void  ast32(u32* p, u32 v)  { __hip_atomic_store(p, v, __ATOMIC_RELAXED, __HIP_MEMORY_SCOPE_AGENT); }
DEV int   ald (const int* p)    { return __hip_atomic_load(p, __ATOMIC_RELAXED, __HIP_MEMORY_SCOPE_AGENT); }

// ---------------- Threefry-2x32-20 (JAX partitionable; R3/R7-verified) ----------------
__host__ __device__ inline void tf2x32(u32 k0, u32 k1, u32 x0, u32 x1, u32& o0, u32& o1){
  u32 k2 = k0 ^ k1 ^ 0x1BD11BDAu;
  x0 += k0; x1 += k1;
#define TFR(r) { x0 += x1; x1 = (x1 << r) | (x1 >> (32 - r)); x1 ^= x0; }
  TFR(13) TFR(15) TFR(26) TFR(6)  x0 += k1; x1 += k2 + 1u;
  TFR(17) TFR(29) TFR(16) TFR(24) x0 += k2; x1 += k0 + 2u;
  TFR(13) TFR(15) TFR(26) TFR(6)  x0 += k0; x1 += k1 + 3u;
  TFR(17) TFR(29) TFR(16) TFR(24) x0 += k1; x1 += k2 + 4u;
  TFR(13) TFR(15) TFR(26) TFR(6)  x0 += k2; x1 += k0 + 5u;
#undef TFR
  o0 = x0; o1 = x1;
}
DEV bool keep_mask(u32 k0, u32 k1, u32 idx){
  u32 a, b; tf2x32(k0, k1, 0u, idx, a, b);
  return (((a ^ b) >> 31) & 1u) == 0u;
}

// ---------------- params ----------------
struct KParams {
  const float *memory, *mels, *pw1, *pw2, *mem_w, *qw, *vw;
  const float *aih, *ahh, *abi, *abh, *dih, *dhh, *dbi, *dbh;
  const float *prw, *prb, *gw, *gb;
  char* ws; float* out;
  u32 k10, k11, k20, k21;
};

__global__ void sentinel_kernel(float* out){ if (threadIdx.x == 0) out[0] = 123.0f; }

// ---------------- sync primitives ----------------
// Post S1: drain write-through payload, join block, fire-and-forget add (tid 0).
DEV void postS1(int* s1cnt, int tid){
  asm volatile("s_waitcnt vmcnt(0)" ::: "memory");
  __syncthreads();
  if (tid == 0)
    (void)__hip_atomic_fetch_add(s1cnt, 1, __ATOMIC_RELAXED, __HIP_MEMORY_SCOPE_AGENT);
}

// Post S2: drain, add with return; LAST of the 32 finishers broadcasts epoch to the
// 32 replica lines (one per 64B) that consumers poll.
DEV void postS2(int* s2cnt, int* rep, int t1, int tid){
  asm volatile("s_waitcnt vmcnt(0)" ::: "memory");
  __syncthreads();
  if (tid == 0){
    int old = __hip_atomic_fetch_add(s2cnt, 1, __ATOMIC_RELAXED, __HIP_MEMORY_SCOPE_AGENT);
    if (old == 32 * t1 - 1){
#pragma unroll
      for (int i = 0; i < 32; i++)
        __hip_atomic_store(&rep[i * 16], t1, __ATOMIC_RELAXED, __HIP_MEMORY_SCOPE_AGENT);
    }
  }
}

// Single-lane counter poll (32 readers max on this line). Acquire-fence on success.
DEV bool waitCnt(int* cnt, int* abortf, int target, int tid, float* out){
  int aborted = 0;
  if (tid == 0){
    int tries = 0;
    while (ald(cnt) < target){
      if (++tries > SPIN){
        __hip_atomic_store(abortf, 1, __ATOMIC_RELAXED, __HIP_MEMORY_SCOPE_AGENT);
        out[1] = 55.0f; aborted = 1; break;
      }
      if ((tries & 255) == 0 && ald(abortf) != 0){ aborted = 1; break; }
      __builtin_amdgcn_s_sleep(2);
    }
  }
  if (__syncthreads_or(aborted)) return false;
  __builtin_amdgcn_fence(__ATOMIC_ACQUIRE, "agent");
  return true;
}

// Single-lane replica poll: block polls its own replica line (~32 readers/line).
DEV bool waitRep(int* repline, int* abortf, int target, int tid, float* out){
  int aborted = 0;
  if (tid == 0){
    int tries = 0;
    while (ald(repline) < target){
      if (++tries > SPIN){
        __hip_atomic_store(abortf, 1, __ATOMIC_RELAXED, __HIP_MEMORY_SCOPE_AGENT);
        out[1] = 55.0f; aborted = 1; break;
      }
      if ((tries & 255) == 0 && ald(abortf) != 0){ aborted = 1; break; }
      __builtin_amdgcn_s_sleep(2);
    }
  }
  if (__syncthreads_or(aborted)) return false;
  __builtin_amdgcn_fence(__ATOMIC_ACQUIRE, "agent");
  return true;
}

// ---------------- persistent decoder ----------------
// Protocol per step t (counters cumulative; t1 = t+1):
//   all:   stage1 -> postS1 -> [service work] -> waitRep(t1) -> stage3
//   att:   after postS1: waitCnt(S1cnt, 1024*t1), attention(b), postS2
//   pre:   after postS1: prenet(t+1), postS2, waitCnt(S1cnt, 1024*t1), proj(t-1)
// S2 epoch broadcast to 32 replica cachelines; every wait is ONE polling lane.
__global__ void __launch_bounds__(NTHR, 2) decoder_kernel(KParams P){
  __shared__ __align__(16) u16 WA[KATT * 4];   // [k][gate] bf16 att weights
  __shared__ __align__(16) u16 WD[KDEC * 4];   // [k][gate] bf16 dec weights
  __shared__ __align__(16) float SCR[1024];
  __shared__ float CATT[16], CDEC[16];
  __shared__ float GBA[4], GBD[4];

  const int blk = blockIdx.x, tid = threadIdx.x;
  int* S1cnt  = (int*)(P.ws + WS_S1CNT);
  int* S2cnt  = (int*)(P.ws + WS_S2CNT);
  int* abortf = (int*)(P.ws + WS_ABORT);
  int* S2rep  = (int*)(P.ws + WS_S2REP);
  int* myrep  = &S2rep[(blk & 31) * 16];
  float* ALN = (float*)(P.ws + WS_ALIGN);          // [2][16][200] (att-block-local)
  float* XA  = (float*)(P.ws + WS_XA);             // [2][1792][16]
  float* XD  = (float*)(P.ws + WS_XD);             // [2][2560][16]
  u16*   PM  = (u16*)(P.ws + WS_PM);               // [3200][128] bf16
  float* out = P.out;

  // ---- one-time: stage this block's LSTM-unit weights into LDS as bf16 ----
#pragma unroll
  for (int g = 0; g < 4; g++){
    const float* rih = P.aih + (size_t)(g * ARNN + blk) * 768;
    for (int k = tid; k < 768; k += NTHR)  WA[k * 4 + g] = f2bf(rih[k]);
    const float* rhh = P.ahh + (size_t)(g * ARNN + blk) * ARNN;
    for (int k = tid; k < ARNN; k += NTHR) WA[(768 + k) * 4 + g] = f2bf(rhh[k]);
    const float* dih = P.dih + (size_t)(g * ARNN + blk) * 1536;
    for (int k = tid; k < 1536; k += NTHR) WD[k * 4 + g] = f2bf(dih[k]);
    const float* dhh = P.dhh + (size_t)(g * ARNN + blk) * ARNN;
    for (int k = tid; k < ARNN; k += NTHR) WD[(1536 + k) * 4 + g] = f2bf(dhh[k]);
  }
  if (tid < 4){
    GBA[tid] = P.abi[tid * ARNN + blk] + P.abh[tid * ARNN + blk];
    GBD[tid] = P.dbi[tid * ARNN + blk] + P.dbh[tid * ARNN + blk];
  }
  if (tid < 16){ CATT[tid] = 0.f; CDEC[tid] = 0.f; }
  if (blk < 16 && tid == 0) ALN[blk * T_ENC] = 1.0f;   // SMA init, parity 0 (block-local)

  // ---- one-time: processed_memory pm[b*200+te][a], published via sc1 u32 stores ----
  for (int rr = 0; rr < 4; rr++){
    int p = blk + rr * NBLK;
    if (p < NB * T_ENC){
      __syncthreads();
      const float4* mrow = (const float4*)(P.memory + (size_t)p * EDIM);
      float4 v = mrow[tid];
      SCR[4 * tid] = v.x; SCR[4 * tid + 1] = v.y;
      SCR[4 * tid + 2] = v.z; SCR[4 * tid + 3] = v.w;
      __syncthreads();
      const float4* w4 = (const float4*)(P.mem_w + (size_t)tid * EDIM);
      float s = 0.f;
      for (int j = 0; j < 128; j++){
        float4 w = w4[j];
        s = fmaf(w.x, SCR[4 * j], s);     s = fmaf(w.y, SCR[4 * j + 1], s);
        s = fmaf(w.z, SCR[4 * j + 2], s); s = fmaf(w.w, SCR[4 * j + 3], s);
      }
      __syncthreads();
      SCR[512 + tid] = s;
      __syncthreads();
      if (tid < 64){
        u32 w2 = (u32)f2bf(SCR[512 + 2 * tid]) | ((u32)f2bf(SCR[512 + 2 * tid + 1]) << 16);
        ast32((u32*)PM + (size_t)p * 64 + tid, w2);
      }
    }
  }

  const int b16 = tid & 15, ks = tid >> 4;

  for (int t = 0; t < T_DEC; t++){
    const int rp = t & 1, wp = rp ^ 1;
    const int t1 = t + 1;
    float* XAr = XA + rp * KATT * 16;
    float* XAw = XA + wp * KATT * 16;
    float* XDr = XD + rp * KDEC * 16;
    float* XDw = XD + wp * KDEC * 16;

    // ======== stage 1: attention LSTM, unit j = blk ========
    {
      float a0 = 0.f, a1 = 0.f, a2 = 0.f, a3 = 0.f;
      int k = ks;
#pragma unroll 8
      for (int i = 0; i < 224; i++, k += 8){
        float x = XAr[k * 16 + b16];
        uint2 wv = *(const uint2*)&WA[k * 4];
        a0 = fmaf(bflo(wv.x), x, a0);
        a1 = fmaf(bfhi(wv.x), x, a1);
        a2 = fmaf(bflo(wv.y), x, a2);
        a3 = fmaf(bfhi(wv.y), x, a3);
      }
      __syncthreads();
      SCR[tid * 4 + 0] = a0; SCR[tid * 4 + 1] = a1;
      SCR[tid * 4 + 2] = a2; SCR[tid * 4 + 3] = a3;
      __syncthreads();
      if (tid < 64){
        int g = tid >> 4, bb = tid & 15;
        float s = 0.f;
#pragma unroll
        for (int q = 0; q < 8; q++) s += SCR[q * 64 + bb * 4 + g];
        SCR[512 + g * 16 + bb] = s;
      }
      __syncthreads();
      if (tid < 16){
        float gi = SCR[512 + tid] + GBA[0];
        float gf = SCR[528 + tid] + GBA[1];
        float gg = SCR[544 + tid] + GBA[2];
        float go = SCR[560 + tid] + GBA[3];
        float cn = fsig(gf) * CATT[tid] + fsig(gi) * ftanh(gg);
        CATT[tid] = cn;
        float h = fsig(go) * ftanh(cn);
        ast(&XAw[(768 + blk) * 16 + tid], h);
        ast(&XDw[blk * 16 + tid], h);
      }
    }
    postS1(S1cnt, tid);

    if (blk < 16){
      // ---- attention chain, batch b = blk ----
      if (!waitCnt(S1cnt, abortf, NBLK * t1, tid, out)) return;
      const int b = blk;
#pragma unroll 4
      for (int i = tid; i < ARNN; i += NTHR) SCR[i] = XAw[(768 + i) * 16 + b];
      __syncthreads();
      float pq = 0.f;
      {
        const float4* q4 = (const float4*)(P.qw + (size_t)tid * ARNN);
        for (int j = 0; j < 256; j++){
          float4 q = q4[j];
          pq = fmaf(q.x, SCR[4 * j], pq);     pq = fmaf(q.y, SCR[4 * j + 1], pq);
          pq = fmaf(q.z, SCR[4 * j + 2], pq); pq = fmaf(q.w, SCR[4 * j + 3], pq);
        }
      }
      __syncthreads();
      SCR[tid] = pq;
      SCR[128 + tid] = P.vw[tid];
      __syncthreads();
#pragma unroll
      for (int pass = 0; pass < 2; pass++){
        int t2 = pass * NTHR + tid;
        if (t2 < T_ENC){
          const u32* pmr = (const u32*)(PM + (size_t)(b * T_ENC + t2) * 128);
          float e = 0.f;
          for (int a2 = 0; a2 < 64; a2++){
            u32 pv = pmr[a2];
            e = fmaf(SCR[128 + 2 * a2],     ftanh(SCR[2 * a2]     + bflo(pv)), e);
            e = fmaf(SCR[128 + 2 * a2 + 1], ftanh(SCR[2 * a2 + 1] + bfhi(pv)), e);
          }
          SCR[256 + t2] = fsig(e);
        }
      }
      __syncthreads();
      const float* alr = ALN + rp * (NB * T_ENC) + b * T_ENC;
      float*       alw = ALN + wp * (NB * T_ENC) + b * T_ENC;
#pragma unroll
      for (int pass = 0; pass < 2; pass++){
        int t2 = pass * NTHR + tid;
        if (t2 < T_ENC){
          float an = alr[t2] * SCR[256 + t2];
          if (t2 > 0) an += alr[t2 - 1] * (1.f - SCR[256 + t2 - 1]);
          SCR[512 + t2] = an;
          alw[t2] = an;
          out[OUT_ALIGN + (size_t)(b * T_DEC + t) * T_ENC + t2] = an;
        }
      }
      __syncthreads();
      {
        const float2* mb = (const float2*)(P.memory + (size_t)b * T_ENC * EDIM);
        float c0 = 0.f, c1 = 0.f, c2 = 0.f, c3 = 0.f;
        for (int s2 = 0; s2 < T_ENC; s2++){
          float as = SCR[512 + s2];
          float2 m1 = mb[(size_t)s2 * 256 + tid];
          float2 m2 = mb[(size_t)s2 * 256 + tid + 128];
          c0 = fmaf(m1.x, as, c0); c1 = fmaf(m1.y, as, c1);
          c2 = fmaf(m2.x, as, c2); c3 = fmaf(m2.y, as, c3);
        }
        int e0 = 2 * tid, e1 = 2 * tid + 256;
        ast(&XAw[(256 + e0) * 16 + b], c0);  ast(&XAw[(256 + e0 + 1) * 16 + b], c1);
        ast(&XAw[(256 + e1) * 16 + b], c2);  ast(&XAw[(256 + e1 + 1) * 16 + b], c3);
        ast(&XDw[(1024 + e0) * 16 + b], c0); ast(&XDw[(1024 + e0 + 1) * 16 + b], c1);
        ast(&XDw[(1024 + e1) * 16 + b], c2); ast(&XDw[(1024 + e1 + 1) * 16 + b], c3);
      }
      postS2(S2cnt, S2rep, t1, tid);
    } else if (blk < 32){
      // ---- prenet for step t+1: no wait (anti-dep covered by prior waitRep) ----
      const int b = blk - 16;
      if (t < T_DEC - 1){
        const int tt = t + 1;
        if (tid < NMEL) SCR[tid] = P.mels[(size_t)(b * NMEL + tid) * T_DEC + t];
        __syncthreads();
#pragma unroll
        for (int pass = 0; pass < 2; pass++){
          int p2 = pass * NTHR + tid;
          const float* wr = P.pw1 + (size_t)p2 * NMEL;
          float s = 0.f;
          for (int m2 = 0; m2 < NMEL; m2++) s = fmaf(wr[m2], SCR[m2], s);
          s = fmaxf(s, 0.f);
          u32 idx = (u32)((tt * NB + b) * PDIM + p2);
          SCR[384 + p2] = keep_mask(P.k10, P.k11, idx) ? 2.f * s : 0.f;
        }
        __syncthreads();
#pragma unroll
        for (int pass = 0; pass < 2; pass++){
          int q2 = pass * NTHR + tid;
          const float* wr = P.pw2 + (size_t)q2 * PDIM;
          float s = 0.f;
          for (int p3 = 0; p3 < PDIM; p3++) s = fmaf(wr[p3], SCR[384 + p3], s);
          s = fmaxf(s, 0.f);
          u32 idx = (u32)((tt * NB + b) * PDIM + q2);
          ast(&XAw[q2 * 16 + b], keep_mask(P.k20, P.k21, idx) ? 2.f * s : 0.f);
        }
      }
      postS2(S2cnt, S2rep, t1, tid);
      // ---- projection(t-1): needs all stage3(t-1) done == S1cnt >= 1024*t1 ----
      if (t > 0){
        if (!waitCnt(S1cnt, abortf, NBLK * t1, tid, out)) return;
        for (int i = tid; i < ARNN; i += NTHR) SCR[i] = XDr[(1536 + i) * 16 + b];
        __syncthreads();
        if (tid < 81){
          const float* wr = (tid < 80) ? P.prw + (size_t)tid * 1536 : P.gw;
          float s = (tid < 80) ? P.prb[tid] : P.gb[0];
          for (int k = 0; k < 1024; k++) s = fmaf(wr[k], SCR[k], s);
          for (int e = 0; e < 512; e++)  s = fmaf(wr[1024 + e], XDr[(1024 + e) * 16 + b], s);
          if (tid < 80) out[(size_t)(b * NMEL + tid) * T_DEC + (t - 1)] = s;
          else          out[OUT_GATE + (size_t)b * T_DEC + (t - 1)] = s;
        }
        __syncthreads();
      }
    }

    if (!waitRep(myrep, abortf, t1, tid, out)) return;

    // ======== stage 3: decoder LSTM, unit j = blk ========
    {
      float a0 = 0.f, a1 = 0.f, a2 = 0.f, a3 = 0.f;
      int k = ks;
#pragma unroll 8
      for (int i = 0; i < 192; i++, k += 8){          // k < 1536: h_att|ctx (this step)
        float x = XDw[k * 16 + b16];
        uint2 wv = *(const uint2*)&WD[k * 4];
        a0 = fmaf(bflo(wv.x), x, a0);
        a1 = fmaf(bfhi(wv.x), x, a1);
        a2 = fmaf(bflo(wv.y), x, a2);
        a3 = fmaf(bfhi(wv.y), x, a3);
      }
#pragma unroll 8
      for (int i = 192; i < 320; i++, k += 8){        // k >= 1536: h_dec (prev step)
        float x = XDr[k * 16 + b16];
        uint2 wv = *(const uint2*)&WD[k * 4];
        a0 = fmaf(bflo(wv.x), x, a0);
        a1 = fmaf(bfhi(wv.x), x, a1);
        a2 = fmaf(bflo(wv.y), x, a2);
        a3 = fmaf(bfhi(wv.y), x, a3);
      }
      __syncthreads();
      SCR[tid * 4 + 0] = a0; SCR[tid * 4 + 1] = a1;
      SCR[tid * 4 + 2] = a2; SCR[tid * 4 + 3] = a3;
      __syncthreads();
      if (tid < 64){
        int g = tid >> 4, bb = tid & 15;
        float s = 0.f;
#pragma unroll
        for (int q = 0; q < 8; q++) s += SCR[q * 64 + bb * 4 + g];
        SCR[512 + g * 16 + bb] = s;
      }
      __syncthreads();
      if (tid < 16){
        float gi = SCR[512 + tid] + GBD[0];
        float gf = SCR[528 + tid] + GBD[1];
        float gg = SCR[544 + tid] + GBD[2];
        float go = SCR[560 + tid] + GBD[3];
        float cn = fsig(gf) * CDEC[tid] + fsig(gi) * ftanh(gg);
        CDEC[tid] = cn;
        float h = fsig(go) * ftanh(cn);
        ast(&XDw[(1536 + blk) * 16 + tid], h);
      }
    }
    // stage3's h stores are drained by next iteration's postS1 vmcnt(0).
  }

  // ---- epilogue: final S1 post, then projection for t = 299 (parity 0) ----
  postS1(S1cnt, tid);
  if (blk >= 16 && blk < 32){
    if (!waitCnt(S1cnt, abortf, NBLK * (T_DEC + 1), tid, out)) return;
    const int b = blk - 16;
    const float* XD0 = XD;   // parity 0
    for (int i = tid; i < ARNN; i += NTHR) SCR[i] = XD0[(1536 + i) * 16 + b];
    __syncthreads();
    if (tid < 81){
      const float* wr = (tid < 80) ? P.prw + (size_t)tid * 1536 : P.gw;
      float s = (tid < 80) ? P.prb[tid] : P.gb[0];
      for (int k = 0; k < 1024; k++) s = fmaf(wr[k], SCR[k], s);
      for (int e = 0; e < 512; e++)  s = fmaf(wr[1024 + e], XD0[(1024 + e) * 16 + b], s);
      if (tid < 80) out[(size_t)(b * NMEL + tid) * T_DEC + (T_DEC - 1)] = s;
      else          out[OUT_GATE + (size_t)b * T_DEC + (T_DEC - 1)] = s;
    }
  }
}

// ---------------- launch ----------------
extern "C" void kernel_launch(void* const* d_in, const int* in_sizes, int n_in,
                              void* d_out, int out_size, void* d_ws, size_t ws_size,
                              hipStream_t stream){
  if (ws_size < (size_t)WS_END){
    hipLaunchKernelGGL(sentinel_kernel, dim3(1), dim3(64), 0, stream, (float*)d_out);
    return;
  }
  hipMemsetAsync(d_ws, 0, (size_t)WS_ZERO, stream);

  KParams P;
  P.memory = (const float*)d_in[0];  P.mels = (const float*)d_in[1];
  P.pw1 = (const float*)d_in[2];     P.pw2 = (const float*)d_in[3];
  P.mem_w = (const float*)d_in[4];   P.qw = (const float*)d_in[5];
  P.vw = (const float*)d_in[6];
  P.aih = (const float*)d_in[7];     P.ahh = (const float*)d_in[8];
  P.abi = (const float*)d_in[9];     P.abh = (const float*)d_in[10];
  P.dih = (const float*)d_in[11];    P.dhh = (const float*)d_in[12];
  P.dbi = (const float*)d_in[13];    P.dbh = (const float*)d_in[14];
  P.prw = (const float*)d_in[15];    P.prb = (const float*)d_in[16];
  P.gw = (const float*)d_in[17];     P.gb = (const float*)d_in[18];
  P.ws = (char*)d_ws; P.out = (float*)d_out;
  tf2x32(0u, 42u, 0u, 0u, P.k10, P.k11);
  tf2x32(0u, 42u, 0u, 1u, P.k20, P.k21);

  hipLaunchKernelGGL(decoder_kernel, dim3(NBLK), dim3(NTHR), 0, stream, P);
}

// Round 4
// 28500.366 us; speedup vs baseline: 2.1069x; 2.1069x over previous
//
#include <hip/hip_runtime.h>

typedef unsigned int u32;
typedef unsigned short u16;
typedef unsigned long long u64;
#define DEV __device__ __forceinline__

// ---------------- sizes ----------------
#define T_DEC 300
#define NB    16
#define T_ENC 200
#define EDIM  512
#define ARNN  1024
#define PDIM  256
#define ADIM  128
#define NMEL  80
#define KATT  1792            // 256 prenet + 512 ctx + 1024 h_att
#define KDEC  2560            // 1024 h_att + 512 ctx + 1024 h_dec
#define NBLK  1024
#define NTHR  128
#define SPIN  2000000         // poll-iteration limit

// ---------------- ws byte offsets ----------------
// counters page [0,4096): S1cnt@0, S2cnt@128, abort@256, S2rep[32]@512 (stride 64B)
#define WS_S1CNT  0
#define WS_S2CNT  128
#define WS_ABORT  256
#define WS_S2REP  512
#define WS_ALIGN  4608                      // f32 [2][16][200] = 25600 (att-block-local)
#define WS_XA     30208                     // f32 [2][896][16][2] = 229376 (paired layout)
#define WS_XD     259584                    // f32 [2][1280][16][2] = 327680 (paired layout)
#define WS_PM     587264                    // u16 [3200][128] = 819200
#define WS_END    1406464
#define WS_ZERO   587264

// paired layout: element (k,b) lives at [(k>>1)*32 + 2*b + (k&1)]
#define XI(k,b) (((k) >> 1) * 32 + 2 * (b) + ((k) & 1))

// ---------------- out layout (f32 elements) ----------------
#define OUT_GATE  (NB*NMEL*T_DEC)           // 384000
#define OUT_ALIGN (OUT_GATE + NB*T_DEC)     // 388800

// ---------------- helpers ----------------
DEV float bflo(u32 u){ return __uint_as_float(u << 16); }
DEV float bfhi(u32 u){ return __uint_as_float(u & 0xffff0000u); }
DEV u16 f2bf(float f){
  u32 u = __float_as_uint(f);
  return (u16)((u + 0x7fffu + ((u >> 16) & 1u)) >> 16);
}
DEV float fsig(float x){ return 1.0f / (1.0f + __expf(-x)); }
DEV float ftanh(float x){
  float xx = fminf(15.0f, fmaxf(-15.0f, x));
  float e = __expf(2.0f * xx);
  return (e - 1.0f) / (e + 1.0f);
}

// ---- coherence-point accessors (sc1): no L2 dirty lines, no fences needed ----
DEV void ast (float* p, float v){ __hip_atomic_store(p, v, __ATOMIC_RELAXED, __HIP_MEMORY_SCOPE_AGENT); }
DEV void ast32(u32* p, u32 v)  { __hip_atomic_store(p, v, __ATOMIC_RELAXED, __HIP_MEMORY_SCOPE_AGENT); }
DEV int  ald (const int* p)    { return __hip_atomic_load(p, __ATOMIC_RELAXED, __HIP_MEMORY_SCOPE_AGENT); }
DEV void ald2f(const float* p, float& f0, float& f1){
  u64 v = __hip_atomic_load((const u64*)p, __ATOMIC_RELAXED, __HIP_MEMORY_SCOPE_AGENT);
  f0 = __uint_as_float((u32)v);
  f1 = __uint_as_float((u32)(v >> 32));
}
DEV void ast2f(float* p, float f0, float f1){
  u64 v = (u64)__float_as_uint(f0) | ((u64)__float_as_uint(f1) << 32);
  __hip_atomic_store((u64*)p, v, __ATOMIC_RELAXED, __HIP_MEMORY_SCOPE_AGENT);
}

// ---------------- Threefry-2x32-20 (JAX partitionable; R3/R7-verified) ----------------
__host__ __device__ inline void tf2x32(u32 k0, u32 k1, u32 x0, u32 x1, u32& o0, u32& o1){
  u32 k2 = k0 ^ k1 ^ 0x1BD11BDAu;
  x0 += k0; x1 += k1;
#define TFR(r) { x0 += x1; x1 = (x1 << r) | (x1 >> (32 - r)); x1 ^= x0; }
  TFR(13) TFR(15) TFR(26) TFR(6)  x0 += k1; x1 += k2 + 1u;
  TFR(17) TFR(29) TFR(16) TFR(24) x0 += k2; x1 += k0 + 2u;
  TFR(13) TFR(15) TFR(26) TFR(6)  x0 += k0; x1 += k1 + 3u;
  TFR(17) TFR(29) TFR(16) TFR(24) x0 += k1; x1 += k2 + 4u;
  TFR(13) TFR(15) TFR(26) TFR(6)  x0 += k2; x1 += k0 + 5u;
#undef TFR
  o0 = x0; o1 = x1;
}
DEV bool keep_mask(u32 k0, u32 k1, u32 idx){
  u32 a, b; tf2x32(k0, k1, 0u, idx, a, b);
  return (((a ^ b) >> 31) & 1u) == 0u;
}

// ---------------- params ----------------
struct KParams {
  const float *memory, *mels, *pw1, *pw2, *mem_w, *qw, *vw;
  const float *aih, *ahh, *abi, *abh, *dih, *dhh, *dbi, *dbh;
  const float *prw, *prb, *gw, *gb;
  char* ws; float* out;
  u32 k10, k11, k20, k21;
};

__global__ void sentinel_kernel(float* out){ if (threadIdx.x == 0) out[0] = 123.0f; }

// ---------------- sync primitives (fence-free) ----------------
// Post S1: drain own sc1 traffic, join block, fire-and-forget add (tid 0).
DEV void postS1(int* s1cnt, int tid){
  asm volatile("s_waitcnt vmcnt(0)" ::: "memory");
  __syncthreads();
  if (tid == 0)
    (void)__hip_atomic_fetch_add(s1cnt, 1, __ATOMIC_RELAXED, __HIP_MEMORY_SCOPE_AGENT);
}

// Post S2: drain, add with return; LAST of 32 finishers broadcasts epoch to 32 replica lines.
DEV void postS2(int* s2cnt, int* rep, int t1, int tid){
  asm volatile("s_waitcnt vmcnt(0)" ::: "memory");
  __syncthreads();
  if (tid == 0){
    int old = __hip_atomic_fetch_add(s2cnt, 1, __ATOMIC_RELAXED, __HIP_MEMORY_SCOPE_AGENT);
    if (old == 32 * t1 - 1){
#pragma unroll
      for (int i = 0; i < 32; i++)
        __hip_atomic_store(&rep[i * 16], t1, __ATOMIC_RELAXED, __HIP_MEMORY_SCOPE_AGENT);
    }
  }
}

// Single-lane counter poll. NO acquire fence: payload is read via sc1 loads.
DEV bool waitCnt(int* cnt, int* abortf, int target, int tid, float* out){
  int aborted = 0;
  if (tid == 0){
    int tries = 0;
    while (ald(cnt) < target){
      if (++tries > SPIN){
        __hip_atomic_store(abortf, 1, __ATOMIC_RELAXED, __HIP_MEMORY_SCOPE_AGENT);
        out[1] = 55.0f; aborted = 1; break;
      }
      if ((tries & 255) == 0 && ald(abortf) != 0){ aborted = 1; break; }
      __builtin_amdgcn_s_sleep(2);
    }
  }
  if (__syncthreads_or(aborted)) return false;
  return true;
}

// Single-lane replica poll. NO acquire fence.
DEV bool waitRep(int* repline, int* abortf, int target, int tid, float* out){
  int aborted = 0;
  if (tid == 0){
    int tries = 0;
    while (ald(repline) < target){
      if (++tries > SPIN){
        __hip_atomic_store(abortf, 1, __ATOMIC_RELAXED, __HIP_MEMORY_SCOPE_AGENT);
        out[1] = 55.0f; aborted = 1; break;
      }
      if ((tries & 255) == 0 && ald(abortf) != 0){ aborted = 1; break; }
      __builtin_amdgcn_s_sleep(2);
    }
  }
  if (__syncthreads_or(aborted)) return false;
  return true;
}

// ---------------- persistent decoder ----------------
// FENCE-FREE protocol: mutable cross-block payload (XA/XD) written AND read with
// relaxed agent atomics (sc1, coherence point). Immutable data (weights, memory,
// mels, PM-after-init) read with plain cached loads — never invalidated, L2-warm.
// Ordering: producer vmcnt(0)-drains before flag post; consumer's sc1 loads issue
// after poll-branch resolution; both meet at the coherence point.
__global__ void __launch_bounds__(NTHR, 2) decoder_kernel(KParams P){
  __shared__ __align__(16) u16 WA[KATT * 4];   // [k][gate] bf16 att weights
  __shared__ __align__(16) u16 WD[KDEC * 4];   // [k][gate] bf16 dec weights
  __shared__ __align__(16) float SCR[1024];
  __shared__ float CATT[16], CDEC[16];
  __shared__ float GBA[4], GBD[4];

  const int blk = blockIdx.x, tid = threadIdx.x;
  int* S1cnt  = (int*)(P.ws + WS_S1CNT);
  int* S2cnt  = (int*)(P.ws + WS_S2CNT);
  int* abortf = (int*)(P.ws + WS_ABORT);
  int* S2rep  = (int*)(P.ws + WS_S2REP);
  int* myrep  = &S2rep[(blk & 31) * 16];
  float* ALN = (float*)(P.ws + WS_ALIGN);          // [2][16][200] (att-block-local, plain)
  float* XA  = (float*)(P.ws + WS_XA);             // [2] paired [896][16][2]
  float* XD  = (float*)(P.ws + WS_XD);             // [2] paired [1280][16][2]
  u16*   PM  = (u16*)(P.ws + WS_PM);               // [3200][128] bf16 (const after init)
  float* out = P.out;

  // ---- one-time: stage this block's LSTM-unit weights into LDS as bf16 ----
#pragma unroll
  for (int g = 0; g < 4; g++){
    const float* rih = P.aih + (size_t)(g * ARNN + blk) * 768;
    for (int k = tid; k < 768; k += NTHR)  WA[k * 4 + g] = f2bf(rih[k]);
    const float* rhh = P.ahh + (size_t)(g * ARNN + blk) * ARNN;
    for (int k = tid; k < ARNN; k += NTHR) WA[(768 + k) * 4 + g] = f2bf(rhh[k]);
    const float* dih = P.dih + (size_t)(g * ARNN + blk) * 1536;
    for (int k = tid; k < 1536; k += NTHR) WD[k * 4 + g] = f2bf(dih[k]);
    const float* dhh = P.dhh + (size_t)(g * ARNN + blk) * ARNN;
    for (int k = tid; k < ARNN; k += NTHR) WD[(1536 + k) * 4 + g] = f2bf(dhh[k]);
  }
  if (tid < 4){
    GBA[tid] = P.abi[tid * ARNN + blk] + P.abh[tid * ARNN + blk];
    GBD[tid] = P.dbi[tid * ARNN + blk] + P.dbh[tid * ARNN + blk];
  }
  if (tid < 16){ CATT[tid] = 0.f; CDEC[tid] = 0.f; }
  if (blk < 16 && tid == 0) ALN[blk * T_ENC] = 1.0f;   // SMA init, parity 0 (block-local)

  // ---- one-time: processed_memory pm[b*200+te][a], published via sc1 u32 stores ----
  for (int rr = 0; rr < 4; rr++){
    int p = blk + rr * NBLK;
    if (p < NB * T_ENC){
      __syncthreads();
      const float4* mrow = (const float4*)(P.memory + (size_t)p * EDIM);
      float4 v = mrow[tid];
      SCR[4 * tid] = v.x; SCR[4 * tid + 1] = v.y;
      SCR[4 * tid + 2] = v.z; SCR[4 * tid + 3] = v.w;
      __syncthreads();
      const float4* w4 = (const float4*)(P.mem_w + (size_t)tid * EDIM);
      float s = 0.f;
      for (int j = 0; j < 128; j++){
        float4 w = w4[j];
        s = fmaf(w.x, SCR[4 * j], s);     s = fmaf(w.y, SCR[4 * j + 1], s);
        s = fmaf(w.z, SCR[4 * j + 2], s); s = fmaf(w.w, SCR[4 * j + 3], s);
      }
      __syncthreads();
      SCR[512 + tid] = s;
      __syncthreads();
      if (tid < 64){
        u32 w2 = (u32)f2bf(SCR[512 + 2 * tid]) | ((u32)f2bf(SCR[512 + 2 * tid + 1]) << 16);
        ast32((u32*)PM + (size_t)p * 64 + tid, w2);
      }
    }
  }

  const int b16 = tid & 15, ks = tid >> 4;

  for (int t = 0; t < T_DEC; t++){
    const int rp = t & 1, wp = rp ^ 1;
    const int t1 = t + 1;
    float* XAr = XA + rp * (KATT * 16);
    float* XAw = XA + wp * (KATT * 16);
    float* XDr = XD + rp * (KDEC * 16);
    float* XDw = XD + wp * (KDEC * 16);

    // ======== stage 1: attention LSTM, unit j = blk (paired sc1 loads) ========
    {
      float a0 = 0.f, a1 = 0.f, a2 = 0.f, a3 = 0.f;
      int kp = ks;
#pragma unroll 8
      for (int i = 0; i < 112; i++, kp += 8){
        float x0, x1;
        ald2f(&XAr[kp * 32 + 2 * b16], x0, x1);
        uint4 wv = *(const uint4*)&WA[kp * 8];     // rows 2kp (x,y) and 2kp+1 (z,w)
        a0 = fmaf(bflo(wv.x), x0, a0); a0 = fmaf(bflo(wv.z), x1, a0);
        a1 = fmaf(bfhi(wv.x), x0, a1); a1 = fmaf(bfhi(wv.z), x1, a1);
        a2 = fmaf(bflo(wv.y), x0, a2); a2 = fmaf(bflo(wv.w), x1, a2);
        a3 = fmaf(bfhi(wv.y), x0, a3); a3 = fmaf(bfhi(wv.w), x1, a3);
      }
      __syncthreads();
      SCR[tid * 4 + 0] = a0; SCR[tid * 4 + 1] = a1;
      SCR[tid * 4 + 2] = a2; SCR[tid * 4 + 3] = a3;
      __syncthreads();
      if (tid < 64){
        int g = tid >> 4, bb = tid & 15;
        float s = 0.f;
#pragma unroll
        for (int q = 0; q < 8; q++) s += SCR[q * 64 + bb * 4 + g];
        SCR[512 + g * 16 + bb] = s;
      }
      __syncthreads();
      if (tid < 16){
        float gi = SCR[512 + tid] + GBA[0];
        float gf = SCR[528 + tid] + GBA[1];
        float gg = SCR[544 + tid] + GBA[2];
        float go = SCR[560 + tid] + GBA[3];
        float cn = fsig(gf) * CATT[tid] + fsig(gi) * ftanh(gg);
        CATT[tid] = cn;
        float h = fsig(go) * ftanh(cn);
        ast(&XAw[XI(768 + blk, tid)], h);
        ast(&XDw[XI(blk, tid)], h);
      }
    }
    postS1(S1cnt, tid);

    if (blk < 16){
      // ---- attention chain, batch b = blk ----
      if (!waitCnt(S1cnt, abortf, NBLK * t1, tid, out)) return;
      const int b = blk;
#pragma unroll 4
      for (int j = tid; j < 512; j += NTHR){       // h_att rows 768..1791, paired
        float h0, h1; ald2f(&XAw[(384 + j) * 32 + 2 * b], h0, h1);
        SCR[2 * j] = h0; SCR[2 * j + 1] = h1;
      }
      __syncthreads();
      float pq = 0.f;
      {
        const float4* q4 = (const float4*)(P.qw + (size_t)tid * ARNN);
        for (int j = 0; j < 256; j++){
          float4 q = q4[j];
          pq = fmaf(q.x, SCR[4 * j], pq);     pq = fmaf(q.y, SCR[4 * j + 1], pq);
          pq = fmaf(q.z, SCR[4 * j + 2], pq); pq = fmaf(q.w, SCR[4 * j + 3], pq);
        }
      }
      __syncthreads();
      SCR[tid] = pq;
      SCR[128 + tid] = P.vw[tid];
      __syncthreads();
#pragma unroll
      for (int pass = 0; pass < 2; pass++){
        int t2 = pass * NTHR + tid;
        if (t2 < T_ENC){
          const u32* pmr = (const u32*)(PM + (size_t)(b * T_ENC + t2) * 128);  // plain (const)
          float e = 0.f;
          for (int a2 = 0; a2 < 64; a2++){
            u32 pv = pmr[a2];
            e = fmaf(SCR[128 + 2 * a2],     ftanh(SCR[2 * a2]     + bflo(pv)), e);
            e = fmaf(SCR[128 + 2 * a2 + 1], ftanh(SCR[2 * a2 + 1] + bfhi(pv)), e);
          }
          SCR[256 + t2] = fsig(e);
        }
      }
      __syncthreads();
      const float* alr = ALN + rp * (NB * T_ENC) + b * T_ENC;   // block-local, plain
      float*       alw = ALN + wp * (NB * T_ENC) + b * T_ENC;
#pragma unroll
      for (int pass = 0; pass < 2; pass++){
        int t2 = pass * NTHR + tid;
        if (t2 < T_ENC){
          float an = alr[t2] * SCR[256 + t2];
          if (t2 > 0) an += alr[t2 - 1] * (1.f - SCR[256 + t2 - 1]);
          SCR[512 + t2] = an;
          alw[t2] = an;
          out[OUT_ALIGN + (size_t)(b * T_DEC + t) * T_ENC + t2] = an;
        }
      }
      __syncthreads();
      {
        const float2* mb = (const float2*)(P.memory + (size_t)b * T_ENC * EDIM);  // plain (const)
        float c0 = 0.f, c1 = 0.f, c2 = 0.f, c3 = 0.f;
        for (int s2 = 0; s2 < T_ENC; s2++){
          float as = SCR[512 + s2];
          float2 m1 = mb[(size_t)s2 * 256 + tid];
          float2 m2 = mb[(size_t)s2 * 256 + tid + 128];
          c0 = fmaf(m1.x, as, c0); c1 = fmaf(m1.y, as, c1);
          c2 = fmaf(m2.x, as, c2); c3 = fmaf(m2.y, as, c3);
        }
        // ctx rows: XA 256+e (pairs 128+tid, 256+tid), XD 1024+e (pairs 512+tid, 640+tid)
        ast2f(&XAw[(128 + tid) * 32 + 2 * b], c0, c1);
        ast2f(&XAw[(256 + tid) * 32 + 2 * b], c2, c3);
        ast2f(&XDw[(512 + tid) * 32 + 2 * b], c0, c1);
        ast2f(&XDw[(640 + tid) * 32 + 2 * b], c2, c3);
      }
      postS2(S2cnt, S2rep, t1, tid);
    } else if (blk < 32){
      // ---- prenet for step t+1: no wait (anti-dep covered by prior waitRep) ----
      const int b = blk - 16;
      if (t < T_DEC - 1){
        const int tt = t + 1;
        if (tid < NMEL) SCR[tid] = P.mels[(size_t)(b * NMEL + tid) * T_DEC + t];  // plain (const)
        __syncthreads();
#pragma unroll
        for (int pass = 0; pass < 2; pass++){
          int p2 = pass * NTHR + tid;
          const float* wr = P.pw1 + (size_t)p2 * NMEL;
          float s = 0.f;
          for (int m2 = 0; m2 < NMEL; m2++) s = fmaf(wr[m2], SCR[m2], s);
          s = fmaxf(s, 0.f);
          u32 idx = (u32)((tt * NB + b) * PDIM + p2);
          SCR[384 + p2] = keep_mask(P.k10, P.k11, idx) ? 2.f * s : 0.f;
        }
        __syncthreads();
        {
          // second layer: thread owns q-pair (2tid, 2tid+1) -> one paired store
          const float* w0 = P.pw2 + (size_t)(2 * tid) * PDIM;
          float s0 = 0.f, s1 = 0.f;
          for (int p3 = 0; p3 < PDIM; p3++){
            float xv = SCR[384 + p3];
            s0 = fmaf(w0[p3], xv, s0);
            s1 = fmaf(w0[PDIM + p3], xv, s1);
          }
          s0 = fmaxf(s0, 0.f); s1 = fmaxf(s1, 0.f);
          u32 i0 = (u32)((tt * NB + b) * PDIM + 2 * tid);
          ast2f(&XAw[tid * 32 + 2 * b],
                keep_mask(P.k20, P.k21, i0)      ? 2.f * s0 : 0.f,
                keep_mask(P.k20, P.k21, i0 + 1u) ? 2.f * s1 : 0.f);
        }
      }
      postS2(S2cnt, S2rep, t1, tid);
      // ---- projection(t-1): needs all stage3(t-1) done == S1cnt >= 1024*t1 ----
      if (t > 0){
        if (!waitCnt(S1cnt, abortf, NBLK * t1, tid, out)) return;
#pragma unroll 4
        for (int j = tid; j < 512; j += NTHR){     // h_dec rows 1536.., pairs 768+j
          float h0, h1; ald2f(&XDr[(768 + j) * 32 + 2 * b], h0, h1);
          SCR[2 * j] = h0; SCR[2 * j + 1] = h1;
        }
        __syncthreads();
        float s = 0.f; const float* wr = 0;
        if (tid < 81){
          wr = (tid < 80) ? P.prw + (size_t)tid * 1536 : P.gw;    // plain (const)
          s = (tid < 80) ? P.prb[tid] : P.gb[0];
          for (int k = 0; k < 1024; k++) s = fmaf(wr[k], SCR[k], s);
        }
        __syncthreads();
#pragma unroll 2
        for (int j = tid; j < 256; j += NTHR){     // ctx rows 1024+e, pairs 512+j
          float f0, f1; ald2f(&XDr[(512 + j) * 32 + 2 * b], f0, f1);
          SCR[2 * j] = f0; SCR[2 * j + 1] = f1;
        }
        __syncthreads();
        if (tid < 81){
          for (int e = 0; e < 512; e++) s = fmaf(wr[1024 + e], SCR[e], s);
          if (tid < 80) out[(size_t)(b * NMEL + tid) * T_DEC + (t - 1)] = s;
          else          out[OUT_GATE + (size_t)b * T_DEC + (t - 1)] = s;
        }
        __syncthreads();
      }
    }

    if (!waitRep(myrep, abortf, t1, tid, out)) return;

    // ======== stage 3: decoder LSTM, unit j = blk (paired sc1 loads) ========
    {
      float a0 = 0.f, a1 = 0.f, a2 = 0.f, a3 = 0.f;
      int kp = ks;
#pragma unroll 8
      for (int i = 0; i < 96; i++, kp += 8){       // kp < 768: h_att|ctx (this step)
        float x0, x1;
        ald2f(&XDw[kp * 32 + 2 * b16], x0, x1);
        uint4 wv = *(const uint4*)&WD[kp * 8];
        a0 = fmaf(bflo(wv.x), x0, a0); a0 = fmaf(bflo(wv.z), x1, a0);
        a1 = fmaf(bfhi(wv.x), x0, a1); a1 = fmaf(bfhi(wv.z), x1, a1);
        a2 = fmaf(bflo(wv.y), x0, a2); a2 = fmaf(bflo(wv.w), x1, a2);
        a3 = fmaf(bfhi(wv.y), x0, a3); a3 = fmaf(bfhi(wv.w), x1, a3);
      }
#pragma unroll 8
      for (int i = 0; i < 64; i++, kp += 8){       // kp >= 768: h_dec (prev step)
        float x0, x1;
        ald2f(&XDr[kp * 32 + 2 * b16], x0, x1);
        uint4 wv = *(const uint4*)&WD[kp * 8];
        a0 = fmaf(bflo(wv.x), x0, a0); a0 = fmaf(bflo(wv.z), x1, a0);
        a1 = fmaf(bfhi(wv.x), x0, a1); a1 = fmaf(bfhi(wv.z), x1, a1);
        a2 = fmaf(bflo(wv.y), x0, a2); a2 = fmaf(bflo(wv.w), x1, a2);
        a3 = fmaf(bfhi(wv.y), x0, a3); a3 = fmaf(bfhi(wv.w), x1, a3);
      }
      __syncthreads();
      SCR[tid * 4 + 0] = a0; SCR[tid * 4 + 1] = a1;
      SCR[tid * 4 + 2] = a2; SCR[tid * 4 + 3] = a3;
      __syncthreads();
      if (tid < 64){
        int g = tid >> 4, bb = tid & 15;
        float s = 0.f;
#pragma unroll
        for (int q = 0; q < 8; q++) s += SCR[q * 64 + bb * 4 + g];
        SCR[512 + g * 16 + bb] = s;
      }
      __syncthreads();
      if (tid < 16){
        float gi = SCR[512 + tid] + GBD[0];
        float gf = SCR[528 + tid] + GBD[1];
        float gg = SCR[544 + tid] + GBD[2];
        float go = SCR[560 + tid] + GBD[3];
        float cn = fsig(gf) * CDEC[tid] + fsig(gi) * ftanh(gg);
        CDEC[tid] = cn;
        float h = fsig(go) * ftanh(cn);
        ast(&XDw[XI(1536 + blk, tid)], h);
      }
    }
    // stage3's h stores drained by next iteration's postS1 vmcnt(0).
  }

  // ---- epilogue: final S1 post, then projection for t = 299 (parity 0) ----
  postS1(S1cnt, tid);
  if (blk >= 16 && blk < 32){
    if (!waitCnt(S1cnt, abortf, NBLK * (T_DEC + 1), tid, out)) return;
    const int b = blk - 16;
    const float* XD0 = XD;   // parity 0
#pragma unroll 4
    for (int j = tid; j < 512; j += NTHR){
      float h0, h1; ald2f(&XD0[(768 + j) * 32 + 2 * b], h0, h1);
      SCR[2 * j] = h0; SCR[2 * j + 1] = h1;
    }
    __syncthreads();
    float s = 0.f; const float* wr = 0;
    if (tid < 81){
      wr = (tid < 80) ? P.prw + (size_t)tid * 1536 : P.gw;
      s = (tid < 80) ? P.prb[tid] : P.gb[0];
      for (int k = 0; k < 1024; k++) s = fmaf(wr[k], SCR[k], s);
    }
    __syncthreads();
#pragma unroll 2
    for (int j = tid; j < 256; j += NTHR){
      float f0, f1; ald2f(&XD0[(512 + j) * 32 + 2 * b], f0, f1);
      SCR[2 * j] = f0; SCR[2 * j + 1] = f1;
    }
    __syncthreads();
    if (tid < 81){
      for (int e = 0; e < 512; e++) s = fmaf(wr[1024 + e], SCR[e], s);
      if (tid < 80) out[(size_t)(b * NMEL + tid) * T_DEC + (T_DEC - 1)] = s;
      else          out[OUT_GATE + (size_t)b * T_DEC + (T_DEC - 1)] = s;
    }
  }
}

// ---------------- launch ----------------
extern "C" void kernel_launch(void* const* d_in, const int* in_sizes, int n_in,
                              void* d_out, int out_size, void* d_ws, size_t ws_size,
                              hipStream_t stream){
  if (ws_size < (size_t)WS_END){
    hipLaunchKernelGGL(sentinel_kernel, dim3(1), dim3(64), 0, stream, (float*)d_out);
    return;
  }
  hipMemsetAsync(d_ws, 0, (size_t)WS_ZERO, stream);

  KParams P;
  P.memory = (const float*)d_in[0];  P.mels = (const float*)d_in[1];
  P.pw1 = (const float*)d_in[2];     P.pw2 = (const float*)d_in[3];
  P.mem_w = (const float*)d_in[4];   P.qw = (const float*)d_in[5];
  P.vw = (const float*)d_in[6];
  P.aih = (const float*)d_in[7];     P.ahh = (const float*)d_in[8];
  P.abi = (const float*)d_in[9];     P.abh = (const float*)d_in[10];
  P.dih = (const float*)d_in[11];    P.dhh = (const float*)d_in[12];
  P.dbi = (const float*)d_in[13];    P.dbh = (const float*)d_in[14];
  P.prw = (const float*)d_in[15];    P.prb = (const float*)d_in[16];
  P.gw = (const float*)d_in[17];     P.gb = (const float*)d_in[18];
  P.ws = (char*)d_ws; P.out = (float*)d_out;
  tf2x32(0u, 42u, 0u, 0u, P.k10, P.k11);
  tf2x32(0u, 42u, 0u, 1u, P.k20, P.k21);

  hipLaunchKernelGGL(decoder_kernel, dim3(NBLK), dim3(NTHR), 0, stream, P);
}